// Round 13
// baseline (2822.008 us; speedup 1.0000x reference)
//
#include <hip/hip_runtime.h>

typedef __attribute__((ext_vector_type(8))) short short8;
typedef __attribute__((ext_vector_type(4))) float f32x4;

__device__ __forceinline__ float silu_f(float x) { return x / (1.0f + __expf(-x)); }

__device__ __forceinline__ unsigned short f2bf(float x) {
  unsigned u = __float_as_uint(x);
  u += 0x7FFFu + ((u >> 16) & 1u);
  return (unsigned short)(u >> 16);
}
__device__ __forceinline__ float bf2f(unsigned short v) {
  return __uint_as_float(((unsigned)v) << 16);
}
__device__ __forceinline__ unsigned cvtpk_bf16(float lo, float hi) {
  unsigned r;
  asm("v_cvt_pk_bf16_f32 %0, %1, %2" : "=v"(r) : "v"(lo), "v"(hi));
  return r;
}

// same-wave LDS write->read fence (no inter-wave barrier); sched_barrier per rule #18
#define LGKM_SB() do { asm volatile("s_waitcnt lgkmcnt(0)" ::: "memory"); \
                       __builtin_amdgcn_sched_barrier(0); } while (0)

// ---------------- weight prep (fused): W[K][N] f32 -> panel-swizzled bf16 hi/lo ----------------
__device__ __forceinline__ void prep_one(const float* __restrict__ W,
                                         unsigned short* __restrict__ wh,
                                         unsigned short* __restrict__ wl,
                                         int N, int e)
{
  int k = e / N, n = e % N;
  float w = W[e];
  unsigned short hi = f2bf(w);
  unsigned short lo = f2bf(w - bf2f(hi));
  int kp = k >> 6, kk = k & 63;
  size_t dst = (size_t)kp * N * 64 + (size_t)n * 64 + ((((kk >> 3) ^ (n & 7)) << 3)) + (kk & 7);
  wh[dst] = hi;
  wl[dst] = lo;
}

__global__ void prep_all(const float* __restrict__ W1, unsigned short* w1h, unsigned short* w1l,
                         const float* __restrict__ W2, unsigned short* w2h, unsigned short* w2l,
                         const float* __restrict__ Wo, unsigned short* woh, unsigned short* wol)
{
  int e = blockIdx.x * 256 + threadIdx.x;
  if (e < 256 * 256) {
    prep_one(W1, w1h, w1l, 256, e);
    prep_one(W2, w2h, w2l, 256, e);
  }
  if (e < 128 * 128) prep_one(Wo, woh, wol, 128, e);
}

// fragment-order bf16 weights for the triplet kernel (same mapping as the old LDS staging)
__global__ void prep_frag(const float* __restrict__ Ws01, const float* __restrict__ Ws02,
                          const float* __restrict__ Ws,
                          unsigned short* __restrict__ w01, unsigned short* __restrict__ w02,
                          unsigned short* __restrict__ wA,  unsigned short* __restrict__ wB)
{
  int e = blockIdx.x * 256 + threadIdx.x;
  if (e >= 16384) return;
  const int j = e & 7, ln = (e >> 3) & 63, ks = (e >> 9) & 3, ct = e >> 11;
  const int col = 16 * ct + (ln & 15);
  const int k = 32 * ks + 8 * (ln >> 4) + j;
  const int src = k * 128 + col;
  w01[e] = f2bf(Ws01[src]);
  w02[e] = f2bf(Ws02[src]);
  wA[e]  = f2bf(Ws[src]);
  wB[e]  = f2bf(Ws[16384 + src]);
}

// ---------------- MLP GEMM: C = silu(A @ W + b), K=256, N=256, bf16 out ----------------
template<int INBF, int ASPLIT>
__global__ __launch_bounds__(512)
void mlp_gemm(const void* A_, const unsigned short* __restrict__ wh,
              const unsigned short* __restrict__ wl,
              const float* __restrict__ bias, unsigned short* __restrict__ C, int M)
{
  __shared__ unsigned short aTh[64 * 64], aTl[64 * 64];
  __shared__ unsigned short whb[256 * 64], wlb[256 * 64];
  const int tid = threadIdx.x;
  const int lane = tid & 63, wv = tid >> 6;
  const int g = wv & 3, hh = wv >> 2;
  const int l15 = lane & 15, l4 = lane >> 4;
  const int row0 = blockIdx.x * 64;
  const int r = tid >> 3, kseg = (tid & 7) * 8;
  const f32x4 zero4 = {0.f, 0.f, 0.f, 0.f};

  f32x4 acc[8];
#pragma unroll
  for (int nt = 0; nt < 8; nt++) acc[nt] = zero4;

  for (int kp = 0; kp < 4; kp++) {
    {
      const int grow = row0 + r;
      float x[8];
      if (grow < M) {
        if (INBF) {
          short8 v = *(const short8*)((const unsigned short*)A_ + (size_t)grow * 256 + kp * 64 + kseg);
#pragma unroll
          for (int j = 0; j < 8; j++) x[j] = bf2f((unsigned short)v[j]);
        } else {
          const float* ap = (const float*)A_ + (size_t)grow * 256 + kp * 64 + kseg;
          float4 v0 = *(const float4*)ap;
          float4 v1 = *(const float4*)(ap + 4);
          x[0] = v0.x; x[1] = v0.y; x[2] = v0.z; x[3] = v0.w;
          x[4] = v1.x; x[5] = v1.y; x[6] = v1.z; x[7] = v1.w;
        }
      } else {
#pragma unroll
        for (int j = 0; j < 8; j++) x[j] = 0.f;
      }
      union { short8 s; unsigned short us[8]; } H, L;
#pragma unroll
      for (int j = 0; j < 8; j++) {
        H.us[j] = f2bf(x[j]);
        L.us[j] = ASPLIT ? f2bf(x[j] - bf2f(H.us[j])) : (unsigned short)0;
      }
      const int dst = r * 64 + ((((kseg >> 3) ^ (r & 7)) << 3));
      *(short8*)(aTh + dst) = H.s;
      if (ASPLIT) *(short8*)(aTl + dst) = L.s;
    }
    {
      const short8* srcH = (const short8*)(wh + (size_t)kp * 16384);
      const short8* srcL = (const short8*)(wl + (size_t)kp * 16384);
#pragma unroll
      for (int i = 0; i < 4; i++) {
        ((short8*)whb)[tid + 512 * i] = srcH[tid + 512 * i];
        ((short8*)wlb)[tid + 512 * i] = srcL[tid + 512 * i];
      }
    }
    __syncthreads();
#pragma unroll
    for (int ks = 0; ks < 2; ks++) {
      const int arow = 16 * g + l15;
      const int aof = arow * 64 + (((4 * ks + l4) ^ (arow & 7)) << 3);
      short8 ah = *(const short8*)(aTh + aof);
      short8 al = *(const short8*)(aTl + aof);
#pragma unroll
      for (int nt = 0; nt < 8; nt++) {
        const int col = 128 * hh + 16 * nt + l15;
        const int bof = col * 64 + (((4 * ks + l4) ^ (col & 7)) << 3);
        short8 bh = *(const short8*)(whb + bof);
        short8 bl = *(const short8*)(wlb + bof);
        acc[nt] = __builtin_amdgcn_mfma_f32_16x16x32_bf16(ah, bh, acc[nt], 0, 0, 0);
        acc[nt] = __builtin_amdgcn_mfma_f32_16x16x32_bf16(ah, bl, acc[nt], 0, 0, 0);
        if (ASPLIT)
          acc[nt] = __builtin_amdgcn_mfma_f32_16x16x32_bf16(al, bh, acc[nt], 0, 0, 0);
      }
    }
    __syncthreads();
  }
#pragma unroll
  for (int nt = 0; nt < 8; nt++) {
    const int col = 128 * hh + 16 * nt + l15;
    const float bv = bias[col];
#pragma unroll
    for (int i = 0; i < 4; i++) {
      const int row = row0 + 16 * g + 4 * l4 + i;
      if (row < M) C[(size_t)row * 256 + col] = f2bf(silu_f(acc[nt][i] + bv));
    }
  }
}

// ---------------- final GEMM: C = A @ Wout + b, K=128, N=128, f32 in/out ----------------
__global__ __launch_bounds__(512)
void final_gemm(const float* __restrict__ A, const unsigned short* __restrict__ wh,
                const unsigned short* __restrict__ wl,
                const float* __restrict__ bias, float* __restrict__ C, int M)
{
  __shared__ unsigned short aTh[64 * 64], aTl[64 * 64];
  __shared__ unsigned short whb[128 * 64], wlb[128 * 64];
  const int tid = threadIdx.x;
  const int lane = tid & 63, wv = tid >> 6;
  const int g = wv & 3, hh = wv >> 2;
  const int l15 = lane & 15, l4 = lane >> 4;
  const int row0 = blockIdx.x * 64;
  const int r = tid >> 3, kseg = (tid & 7) * 8;
  const f32x4 zero4 = {0.f, 0.f, 0.f, 0.f};

  f32x4 acc[4];
#pragma unroll
  for (int nt = 0; nt < 4; nt++) acc[nt] = zero4;

  for (int kp = 0; kp < 2; kp++) {
    {
      const int grow = row0 + r;
      float x[8];
      if (grow < M) {
        const float* ap = A + (size_t)grow * 128 + kp * 64 + kseg;
        float4 v0 = *(const float4*)ap;
        float4 v1 = *(const float4*)(ap + 4);
        x[0] = v0.x; x[1] = v0.y; x[2] = v0.z; x[3] = v0.w;
        x[4] = v1.x; x[5] = v1.y; x[6] = v1.z; x[7] = v1.w;
      } else {
#pragma unroll
        for (int j = 0; j < 8; j++) x[j] = 0.f;
      }
      union { short8 s; unsigned short us[8]; } H, L;
#pragma unroll
      for (int j = 0; j < 8; j++) {
        H.us[j] = f2bf(x[j]);
        L.us[j] = f2bf(x[j] - bf2f(H.us[j]));
      }
      const int dst = r * 64 + ((((kseg >> 3) ^ (r & 7)) << 3));
      *(short8*)(aTh + dst) = H.s;
      *(short8*)(aTl + dst) = L.s;
    }
    {
      const short8* srcH = (const short8*)(wh + (size_t)kp * 8192);
      const short8* srcL = (const short8*)(wl + (size_t)kp * 8192);
#pragma unroll
      for (int i = 0; i < 2; i++) {
        ((short8*)whb)[tid + 512 * i] = srcH[tid + 512 * i];
        ((short8*)wlb)[tid + 512 * i] = srcL[tid + 512 * i];
      }
    }
    __syncthreads();
#pragma unroll
    for (int ks = 0; ks < 2; ks++) {
      const int arow = 16 * g + l15;
      const int aof = arow * 64 + (((4 * ks + l4) ^ (arow & 7)) << 3);
      short8 ah = *(const short8*)(aTh + aof);
      short8 al = *(const short8*)(aTl + aof);
#pragma unroll
      for (int nt = 0; nt < 4; nt++) {
        const int col = 64 * hh + 16 * nt + l15;
        const int bof = col * 64 + (((4 * ks + l4) ^ (col & 7)) << 3);
        short8 bh = *(const short8*)(whb + bof);
        short8 bl = *(const short8*)(wlb + bof);
        acc[nt] = __builtin_amdgcn_mfma_f32_16x16x32_bf16(ah, bh, acc[nt], 0, 0, 0);
        acc[nt] = __builtin_amdgcn_mfma_f32_16x16x32_bf16(ah, bl, acc[nt], 0, 0, 0);
        acc[nt] = __builtin_amdgcn_mfma_f32_16x16x32_bf16(al, bh, acc[nt], 0, 0, 0);
      }
    }
    __syncthreads();
  }
#pragma unroll
  for (int nt = 0; nt < 4; nt++) {
    const int col = 64 * hh + 16 * nt + l15;
    const float bv = bias[col];
#pragma unroll
    for (int i = 0; i < 4; i++) {
      const int row = row0 + 16 * g + 4 * l4 + i;
      if (row < M) C[(size_t)row * 128 + col] = acc[nt][i] + bv;
    }
  }
}

// ---------------- counting sort of idx_ji (proven 3-kernel scan) ----------------
__global__ void hist_k(const int* __restrict__ ji, int* __restrict__ cnt, int T) {
  int t = blockIdx.x * 256 + threadIdx.x;
  const int stride = gridDim.x * 256;
  for (; t < T; t += stride) atomicAdd(&cnt[ji[t]], 1);
}

__global__ void scan1_k(const int* __restrict__ cnt, int* __restrict__ csum, int E) {
  __shared__ int red[256];
  const int c0 = blockIdx.x * 2048;
  int s = 0;
  for (int i = threadIdx.x; i < 2048; i += 256) {
    int e = c0 + i;
    if (e < E) s += cnt[e];
  }
  red[threadIdx.x] = s;
  __syncthreads();
  for (int o = 128; o > 0; o >>= 1) {
    if (threadIdx.x < o) red[threadIdx.x] += red[threadIdx.x + o];
    __syncthreads();
  }
  if (threadIdx.x == 0) csum[blockIdx.x] = red[0];
}

__global__ void scan2_k(int* __restrict__ csum, int n) {
  if (threadIdx.x == 0 && blockIdx.x == 0) {
    int acc = 0;
    for (int i = 0; i < n; i++) { int v = csum[i]; csum[i] = acc; acc += v; }
  }
}

__global__ void scan3_k(const int* __restrict__ cnt, const int* __restrict__ csum,
                        int* __restrict__ off, int E) {
  __shared__ int ts[256];
  const int c0 = blockIdx.x * 2048;
  const int tid = threadIdx.x;
  int loc[8];
  int s = 0;
#pragma unroll
  for (int k = 0; k < 8; k++) {
    int e = c0 + tid * 8 + k;
    loc[k] = (e < E) ? cnt[e] : 0;
    s += loc[k];
  }
  ts[tid] = s;
  __syncthreads();
  for (int o = 1; o < 256; o <<= 1) {
    int v = (tid >= o) ? ts[tid - o] : 0;
    __syncthreads();
    ts[tid] += v;
    __syncthreads();
  }
  int base = csum[blockIdx.x] + ((tid > 0) ? ts[tid - 1] : 0);
#pragma unroll
  for (int k = 0; k < 8; k++) {
    int e = c0 + tid * 8 + k;
    if (e < E) { off[e] = base; base += loc[k]; }
  }
}

__global__ void scatter_k(const int* __restrict__ ji, int* __restrict__ cursor,
                          int* __restrict__ perm, int T) {
  int t = blockIdx.x * 256 + threadIdx.x;
  const int stride = gridDim.x * 256;
  for (; t < T; t += stride) {
    int e = ji[t];
    int p = atomicAdd(&cursor[e], 1);
    perm[p] = t;
  }
}

// ---------------- fused triplet kernel: wave-independent, weights from L2 ----------------
__device__ __forceinline__ short8 pack8p(const short8 a, const short8 b,
                                         const float4 m0, const float4 m1)
{
  float p0 = bf2f((unsigned short)a[0]) * m0.x * bf2f((unsigned short)b[0]);
  float p1 = bf2f((unsigned short)a[1]) * m0.y * bf2f((unsigned short)b[1]);
  float p2 = bf2f((unsigned short)a[2]) * m0.z * bf2f((unsigned short)b[2]);
  float p3 = bf2f((unsigned short)a[3]) * m0.w * bf2f((unsigned short)b[3]);
  float p4 = bf2f((unsigned short)a[4]) * m1.x * bf2f((unsigned short)b[4]);
  float p5 = bf2f((unsigned short)a[5]) * m1.y * bf2f((unsigned short)b[5]);
  float p6 = bf2f((unsigned short)a[6]) * m1.z * bf2f((unsigned short)b[6]);
  float p7 = bf2f((unsigned short)a[7]) * m1.w * bf2f((unsigned short)b[7]);
  union { short8 s; unsigned u[4]; } t;
  t.u[0] = cvtpk_bf16(p0, p1);
  t.u[1] = cvtpk_bf16(p2, p3);
  t.u[2] = cvtpk_bf16(p4, p5);
  t.u[3] = cvtpk_bf16(p6, p7);
  return t.s;
}

// Requires T % 16 == 0 (T = 1e6 -> 62500 subwindows of 16 sorted rows).
// Weights read directly from L2-resident fragment-order global arrays (no LDS staging)
// -> LDS = 32 KB sbuf only -> 2 blocks/CU, 4 waves/SIMD.
__global__ __launch_bounds__(512, 4)
void triplet_fused(const unsigned short* __restrict__ h,
                   const float* __restrict__ M01, const float* __restrict__ M02,
                   const unsigned short* __restrict__ wF01,
                   const unsigned short* __restrict__ wF02,
                   const unsigned short* __restrict__ wFA,
                   const unsigned short* __restrict__ wFB,
                   const float* __restrict__ bs01, const float* __restrict__ bs02,
                   const float* __restrict__ bs,
                   const int* __restrict__ idx_ji, const int* __restrict__ idx_ki,
                   const int* __restrict__ perm,
                   float* __restrict__ out_acc, int T)
{
  __shared__ unsigned short sbuf[8][2048]; // 4 KB per wave (16 rows x 128 cols bf16)

  const int tid = threadIdx.x;
  const int lane = tid & 63, wv = tid >> 6;
  const int l15 = lane & 15, l4 = lane >> 4;
  unsigned short* const sb = sbuf[wv];

  float bs01v[8], bs02v[8], bsv[8];
#pragma unroll
  for (int ct = 0; ct < 8; ct++) {
    bs01v[ct] = bs01[16 * ct + l15];
    bs02v[ct] = bs02[16 * ct + l15];
    bsv[ct]   = bs[16 * ct + l15];
  }

  const int nsub = T >> 4;
  const int stride = gridDim.x * 8;
  int sub = blockIdx.x * 8 + wv;
  if (sub >= nsub) return;

  // prologue: first subwindow's indices
  int pidx = perm[(sub << 4) + l15];
  int ek = idx_ki[pidx], ej = idx_ji[pidx];

  for (; sub < nsub; sub += stride) {
    // ---- issue ALL gathers for this subwindow (per-lane row l15, k-slices 8*l4) ----
    const unsigned short* fa = h + (size_t)ek * 256 + 8 * l4;
    const unsigned short* fb = h + (size_t)ej * 256 + 8 * l4;
    const float* mm1 = M01 + (size_t)pidx * 128 + 8 * l4;
    const float* mm2 = M02 + (size_t)pidx * 128 + 8 * l4;
    short8 ra1[4], rb1[4], ra2[4], rb2[4];
    float4 rm1[8], rm2[8];
#pragma unroll
    for (int ks = 0; ks < 4; ks++) {
      ra1[ks] = *(const short8*)(fa + 32 * ks);
      rb1[ks] = *(const short8*)(fb + 32 * ks);
      rm1[2 * ks]     = *(const float4*)(mm1 + 32 * ks);
      rm1[2 * ks + 1] = *(const float4*)(mm1 + 32 * ks + 4);
      ra2[ks] = *(const short8*)(fa + 128 + 32 * ks);
      rb2[ks] = *(const short8*)(fb + 128 + 32 * ks);
      rm2[2 * ks]     = *(const float4*)(mm2 + 32 * ks);
      rm2[2 * ks + 1] = *(const float4*)(mm2 + 32 * ks + 4);
    }

    // prefetch next subwindow's perm entry (dependent idx loads issued mid-body)
    const int subn = sub + stride;
    int sidx = (subn << 4) + l15;
    if (sidx >= T) sidx = T - 1;             // clamp; values unused past end
    const int pidx_n = perm[sidx];

    // ---- MFMA1: p01 @ Ws01 -> acc1[8]; bias folded into C-init ----
    f32x4 acc1[8];
#pragma unroll
    for (int ct = 0; ct < 8; ct++) {
      const float b = bs01v[ct];
      acc1[ct] = (f32x4){b, b, b, b};
    }
    __builtin_amdgcn_s_setprio(1);
#pragma unroll
    for (int ks = 0; ks < 4; ks++) {
      const short8 a = pack8p(ra1[ks], rb1[ks], rm1[2 * ks], rm1[2 * ks + 1]);
#pragma unroll
      for (int ct = 0; ct < 8; ct++) {
        const short8 b = *(const short8*)(wF01 + ((ct * 4 + ks) * 64 + lane) * 8);
        acc1[ct] = __builtin_amdgcn_mfma_f32_16x16x32_bf16(a, b, acc1[ct], 0, 0, 0);
      }
    }
    __builtin_amdgcn_s_setprio(0);

    // ---- s01 = silu(acc1) -> wave-private sbuf (chunk-XOR swizzle, cvt_pk pairs) ----
#pragma unroll
    for (int ct = 0; ct < 8; ct++) {
      const int chi = 2 * ct + (l15 >> 3);
      const float s0 = silu_f(acc1[ct][0]);
      const float s1 = silu_f(acc1[ct][1]);
      const float s2 = silu_f(acc1[ct][2]);
      const float s3 = silu_f(acc1[ct][3]);
      const unsigned u01 = cvtpk_bf16(s0, s1);
      const unsigned u23 = cvtpk_bf16(s2, s3);
      const int r0 = 4 * l4;
      sb[(r0 + 0) * 128 + (((chi ^ ((r0 + 0) & 7)) << 3)) + (l15 & 7)] = (unsigned short)u01;
      sb[(r0 + 1) * 128 + (((chi ^ ((r0 + 1) & 7)) << 3)) + (l15 & 7)] = (unsigned short)(u01 >> 16);
      sb[(r0 + 2) * 128 + (((chi ^ ((r0 + 2) & 7)) << 3)) + (l15 & 7)] = (unsigned short)u23;
      sb[(r0 + 3) * 128 + (((chi ^ ((r0 + 3) & 7)) << 3)) + (l15 & 7)] = (unsigned short)(u23 >> 16);
    }
    LGKM_SB();
    short8 as1[4];
#pragma unroll
    for (int ks = 0; ks < 4; ks++)
      as1[ks] = *(const short8*)(sb + l15 * 128 + (((4 * ks + l4) ^ (l15 & 7)) << 3));

    // ---- MFMA2: s01 @ WsA -> acc3[8]; final bias folded into C-init ----
    f32x4 acc3[8];
#pragma unroll
    for (int ct = 0; ct < 8; ct++) {
      const float b = bsv[ct];
      acc3[ct] = (f32x4){b, b, b, b};
    }
    __builtin_amdgcn_s_setprio(1);
#pragma unroll
    for (int ks = 0; ks < 4; ks++)
#pragma unroll
      for (int ct = 0; ct < 8; ct++) {
        const short8 b = *(const short8*)(wFA + ((ct * 4 + ks) * 64 + lane) * 8);
        acc3[ct] = __builtin_amdgcn_mfma_f32_16x16x32_bf16(as1[ks], b, acc3[ct], 0, 0, 0);
      }
    __builtin_amdgcn_s_setprio(0);

    // next-subwindow dependent idx loads (covered by MFMA3..4)
    const int ekn = idx_ki[pidx_n], ejn = idx_ji[pidx_n];

    // ---- MFMA3: p02 @ Ws02 -> acc1 (reuse); bias folded ----
#pragma unroll
    for (int ct = 0; ct < 8; ct++) {
      const float b = bs02v[ct];
      acc1[ct] = (f32x4){b, b, b, b};
    }
    __builtin_amdgcn_s_setprio(1);
#pragma unroll
    for (int ks = 0; ks < 4; ks++) {
      const short8 a = pack8p(ra2[ks], rb2[ks], rm2[2 * ks], rm2[2 * ks + 1]);
#pragma unroll
      for (int ct = 0; ct < 8; ct++) {
        const short8 b = *(const short8*)(wF02 + ((ct * 4 + ks) * 64 + lane) * 8);
        acc1[ct] = __builtin_amdgcn_mfma_f32_16x16x32_bf16(a, b, acc1[ct], 0, 0, 0);
      }
    }
    __builtin_amdgcn_s_setprio(0);

    // ---- s02 -> sbuf (as1 already consumed; wave-private, no WAR hazard) ----
#pragma unroll
    for (int ct = 0; ct < 8; ct++) {
      const int chi = 2 * ct + (l15 >> 3);
      const float s0 = silu_f(acc1[ct][0]);
      const float s1 = silu_f(acc1[ct][1]);
      const float s2 = silu_f(acc1[ct][2]);
      const float s3 = silu_f(acc1[ct][3]);
      const unsigned u01 = cvtpk_bf16(s0, s1);
      const unsigned u23 = cvtpk_bf16(s2, s3);
      const int r0 = 4 * l4;
      sb[(r0 + 0) * 128 + (((chi ^ ((r0 + 0) & 7)) << 3)) + (l15 & 7)] = (unsigned short)u01;
      sb[(r0 + 1) * 128 + (((chi ^ ((r0 + 1) & 7)) << 3)) + (l15 & 7)] = (unsigned short)(u01 >> 16);
      sb[(r0 + 2) * 128 + (((chi ^ ((r0 + 2) & 7)) << 3)) + (l15 & 7)] = (unsigned short)u23;
      sb[(r0 + 3) * 128 + (((chi ^ ((r0 + 3) & 7)) << 3)) + (l15 & 7)] = (unsigned short)(u23 >> 16);
    }
    LGKM_SB();
    short8 as2[4];
#pragma unroll
    for (int ks = 0; ks < 4; ks++)
      as2[ks] = *(const short8*)(sb + l15 * 128 + (((4 * ks + l4) ^ (l15 & 7)) << 3));

    // ---- MFMA4: s02 @ WsB -> acc3 += ----
    __builtin_amdgcn_s_setprio(1);
#pragma unroll
    for (int ks = 0; ks < 4; ks++)
#pragma unroll
      for (int ct = 0; ct < 8; ct++) {
        const short8 b = *(const short8*)(wFB + ((ct * 4 + ks) * 64 + lane) * 8);
        acc3[ct] = __builtin_amdgcn_mfma_f32_16x16x32_bf16(as2[ks], b, acc3[ct], 0, 0, 0);
      }
    __builtin_amdgcn_s_setprio(0);

    // ---- sfin = silu(acc3) in place (bias already folded) ----
#pragma unroll
    for (int ct = 0; ct < 8; ct++)
#pragma unroll
      for (int i = 0; i < 4; i++)
        acc3[ct][i] = silu_f(acc3[ct][i]);

    // ---- register segment-sum over 16 sorted rows ----
    {
      const int ejp = __shfl_up(ej, 1, 16);
      unsigned bm = (unsigned)(__ballot((l15 > 0) && (ej != ejp)) & 0xFFFFull);
      int fr = 0;
      unsigned rem = bm;
      while (fr < 16) {
        const int nxt = rem ? (__ffs(rem) - 1) : 16;
        rem &= rem - 1;
        const int lr = nxt - 1;
        const int e = __shfl(ej, fr, 16);
        float sv[8];
#pragma unroll
        for (int ct = 0; ct < 8; ct++) {
          float s = 0.f;
#pragma unroll
          for (int i = 0; i < 4; i++) {
            const int rr = 4 * l4 + i;
            s += (rr >= fr && rr <= lr) ? acc3[ct][i] : 0.f;
          }
          s += __shfl_xor(s, 16);
          s += __shfl_xor(s, 32);
          sv[ct] = s;
        }
        float w0, w1;
        if (l4 == 0)      { w0 = sv[0]; w1 = sv[1]; }
        else if (l4 == 1) { w0 = sv[2]; w1 = sv[3]; }
        else if (l4 == 2) { w0 = sv[4]; w1 = sv[5]; }
        else              { w0 = sv[6]; w1 = sv[7]; }
        float* dst = out_acc + (size_t)e * 128 + 32 * l4 + l15;
        if (fr == 0 || lr == 15) {   // run may continue into adjacent subwindow
          atomicAdd(dst, w0);
          atomicAdd(dst + 16, w1);
        } else {                     // strictly interior -> exclusive
          dst[0] = w0;
          dst[16] = w1;
        }
        fr = nxt;
      }
    }

    pidx = pidx_n; ek = ekn; ej = ejn;
  }
}

extern "C" void kernel_launch(void* const* d_in, const int* in_sizes, int n_in,
                              void* d_out, int out_size, void* d_ws, size_t ws_size,
                              hipStream_t stream)
{
  const float* f    = (const float*)d_in[0];
  const float* M01  = (const float*)d_in[1];
  const float* M02  = (const float*)d_in[2];
  const float* W1   = (const float*)d_in[3];
  const float* b1   = (const float*)d_in[4];
  const float* W2   = (const float*)d_in[5];
  const float* b2   = (const float*)d_in[6];
  const float* Ws01 = (const float*)d_in[7];
  const float* bs01 = (const float*)d_in[8];
  const float* Ws02 = (const float*)d_in[9];
  const float* bs02 = (const float*)d_in[10];
  const float* Ws   = (const float*)d_in[11];
  const float* bs   = (const float*)d_in[12];
  const float* Wout = (const float*)d_in[13];
  const float* bout = (const float*)d_in[14];
  const int* idx_ji = (const int*)d_in[16];
  const int* idx_ki = (const int*)d_in[17];

  const int E = in_sizes[0] / 256;
  const int T = in_sizes[1] / 128;

  char* w = (char*)d_ws;
  unsigned short* hbuf = (unsigned short*)w;                       // [E][256] bf16
  size_t o = ((size_t)E * 256 * 2 + 255) & ~(size_t)255;
  unsigned short* wt1h = (unsigned short*)(w + o); o += 256 * 256 * 2;
  unsigned short* wt1l = (unsigned short*)(w + o); o += 256 * 256 * 2;
  unsigned short* wt2h = (unsigned short*)(w + o); o += 256 * 256 * 2;
  unsigned short* wt2l = (unsigned short*)(w + o); o += 256 * 256 * 2;
  unsigned short* wtoh = (unsigned short*)(w + o); o += 128 * 128 * 2;
  unsigned short* wtol = (unsigned short*)(w + o); o += 128 * 128 * 2;
  unsigned short* wf01 = (unsigned short*)(w + o); o += 16384 * 2;  // fragment-order bf16
  unsigned short* wf02 = (unsigned short*)(w + o); o += 16384 * 2;
  unsigned short* wfA  = (unsigned short*)(w + o); o += 16384 * 2;
  unsigned short* wfB  = (unsigned short*)(w + o); o += 16384 * 2;
  o = (o + 255) & ~(size_t)255;
  int* cnt = (int*)(w + o);  o += ((size_t)E * 4 + 255) & ~(size_t)255;
  int* off = (int*)(w + o);  o += ((size_t)E * 4 + 255) & ~(size_t)255;
  int* csum = (int*)(w + o); o += 4096;
  int* perm = (int*)(w + o);                                       // [T]

  float* out_acc = (float*)d_out;
  const int mb = (E + 63) / 64;

  prep_all<<<(256 * 256 + 255) / 256, 256, 0, stream>>>(W1, wt1h, wt1l,
                                                        W2, wt2h, wt2l,
                                                        Wout, wtoh, wtol);
  prep_frag<<<64, 256, 0, stream>>>(Ws01, Ws02, Ws, wf01, wf02, wfA, wfB);

  mlp_gemm<0, 1><<<mb, 512, 0, stream>>>(f, wt1h, wt1l, b1, hbuf, E);
  mlp_gemm<1, 0><<<mb, 512, 0, stream>>>(hbuf, wt2h, wt2l, b2, hbuf, E);

  hipMemsetAsync(cnt, 0, (size_t)E * 4, stream);
  hist_k<<<1024, 256, 0, stream>>>(idx_ji, cnt, T);
  const int nchunks = (E + 2047) / 2048;
  scan1_k<<<nchunks, 256, 0, stream>>>(cnt, csum, E);
  scan2_k<<<1, 64, 0, stream>>>(csum, nchunks);
  scan3_k<<<nchunks, 256, 0, stream>>>(cnt, csum, off, E);
  scatter_k<<<1024, 256, 0, stream>>>(idx_ji, off, perm, T);

  hipMemsetAsync(d_out, 0, (size_t)E * 128 * sizeof(float), stream);

  triplet_fused<<<512, 512, 0, stream>>>(hbuf, M01, M02, wf01, wf02, wfA, wfB,
                                         bs01, bs02, bs, idx_ji, idx_ki, perm,
                                         out_acc, T);

  final_gemm<<<mb, 512, 0, stream>>>(out_acc, wtoh, wtol, bout, out_acc, E);
}

// Round 14
// 918.344 us; speedup vs baseline: 3.0729x; 3.0729x over previous
//
#include <hip/hip_runtime.h>

typedef __attribute__((ext_vector_type(8))) short short8;
typedef __attribute__((ext_vector_type(4))) float f32x4;

__device__ __forceinline__ float silu_f(float x) { return x / (1.0f + __expf(-x)); }

__device__ __forceinline__ unsigned short f2bf(float x) {
  unsigned u = __float_as_uint(x);
  u += 0x7FFFu + ((u >> 16) & 1u);
  return (unsigned short)(u >> 16);
}
__device__ __forceinline__ float bf2f(unsigned short v) {
  return __uint_as_float(((unsigned)v) << 16);
}
__device__ __forceinline__ unsigned cvtpk_bf16(float lo, float hi) {
  unsigned r;
  asm("v_cvt_pk_bf16_f32 %0, %1, %2" : "=v"(r) : "v"(lo), "v"(hi));
  return r;
}

// same-wave LDS write->read fence (no inter-wave barrier); sched_barrier per rule #18
#define LGKM_SB() do { asm volatile("s_waitcnt lgkmcnt(0)" ::: "memory"); \
                       __builtin_amdgcn_sched_barrier(0); } while (0)

// ---------------- weight prep (fused): W[K][N] f32 -> panel-swizzled bf16 hi/lo ----------------
__device__ __forceinline__ void prep_one(const float* __restrict__ W,
                                         unsigned short* __restrict__ wh,
                                         unsigned short* __restrict__ wl,
                                         int N, int e)
{
  int k = e / N, n = e % N;
  float w = W[e];
  unsigned short hi = f2bf(w);
  unsigned short lo = f2bf(w - bf2f(hi));
  int kp = k >> 6, kk = k & 63;
  size_t dst = (size_t)kp * N * 64 + (size_t)n * 64 + ((((kk >> 3) ^ (n & 7)) << 3)) + (kk & 7);
  wh[dst] = hi;
  wl[dst] = lo;
}

__global__ void prep_all(const float* __restrict__ W1, unsigned short* w1h, unsigned short* w1l,
                         const float* __restrict__ W2, unsigned short* w2h, unsigned short* w2l,
                         const float* __restrict__ Wo, unsigned short* woh, unsigned short* wol)
{
  int e = blockIdx.x * 256 + threadIdx.x;
  if (e < 256 * 256) {
    prep_one(W1, w1h, w1l, 256, e);
    prep_one(W2, w2h, w2l, 256, e);
  }
  if (e < 128 * 128) prep_one(Wo, woh, wol, 128, e);
}

// ---------------- MLP GEMM: C = silu(A @ W + b), K=256, N=256, bf16 out ----------------
template<int INBF, int ASPLIT>
__global__ __launch_bounds__(512)
void mlp_gemm(const void* A_, const unsigned short* __restrict__ wh,
              const unsigned short* __restrict__ wl,
              const float* __restrict__ bias, unsigned short* __restrict__ C, int M)
{
  __shared__ unsigned short aTh[64 * 64], aTl[64 * 64];
  __shared__ unsigned short whb[256 * 64], wlb[256 * 64];
  const int tid = threadIdx.x;
  const int lane = tid & 63, wv = tid >> 6;
  const int g = wv & 3, hh = wv >> 2;
  const int l15 = lane & 15, l4 = lane >> 4;
  const int row0 = blockIdx.x * 64;
  const int r = tid >> 3, kseg = (tid & 7) * 8;
  const f32x4 zero4 = {0.f, 0.f, 0.f, 0.f};

  f32x4 acc[8];
#pragma unroll
  for (int nt = 0; nt < 8; nt++) acc[nt] = zero4;

  for (int kp = 0; kp < 4; kp++) {
    {
      const int grow = row0 + r;
      float x[8];
      if (grow < M) {
        if (INBF) {
          short8 v = *(const short8*)((const unsigned short*)A_ + (size_t)grow * 256 + kp * 64 + kseg);
#pragma unroll
          for (int j = 0; j < 8; j++) x[j] = bf2f((unsigned short)v[j]);
        } else {
          const float* ap = (const float*)A_ + (size_t)grow * 256 + kp * 64 + kseg;
          float4 v0 = *(const float4*)ap;
          float4 v1 = *(const float4*)(ap + 4);
          x[0] = v0.x; x[1] = v0.y; x[2] = v0.z; x[3] = v0.w;
          x[4] = v1.x; x[5] = v1.y; x[6] = v1.z; x[7] = v1.w;
        }
      } else {
#pragma unroll
        for (int j = 0; j < 8; j++) x[j] = 0.f;
      }
      union { short8 s; unsigned short us[8]; } H, L;
#pragma unroll
      for (int j = 0; j < 8; j++) {
        H.us[j] = f2bf(x[j]);
        L.us[j] = ASPLIT ? f2bf(x[j] - bf2f(H.us[j])) : (unsigned short)0;
      }
      const int dst = r * 64 + ((((kseg >> 3) ^ (r & 7)) << 3));
      *(short8*)(aTh + dst) = H.s;
      if (ASPLIT) *(short8*)(aTl + dst) = L.s;
    }
    {
      const short8* srcH = (const short8*)(wh + (size_t)kp * 16384);
      const short8* srcL = (const short8*)(wl + (size_t)kp * 16384);
#pragma unroll
      for (int i = 0; i < 4; i++) {
        ((short8*)whb)[tid + 512 * i] = srcH[tid + 512 * i];
        ((short8*)wlb)[tid + 512 * i] = srcL[tid + 512 * i];
      }
    }
    __syncthreads();
#pragma unroll
    for (int ks = 0; ks < 2; ks++) {
      const int arow = 16 * g + l15;
      const int aof = arow * 64 + (((4 * ks + l4) ^ (arow & 7)) << 3);
      short8 ah = *(const short8*)(aTh + aof);
      short8 al = *(const short8*)(aTl + aof);
#pragma unroll
      for (int nt = 0; nt < 8; nt++) {
        const int col = 128 * hh + 16 * nt + l15;
        const int bof = col * 64 + (((4 * ks + l4) ^ (col & 7)) << 3);
        short8 bh = *(const short8*)(whb + bof);
        short8 bl = *(const short8*)(wlb + bof);
        acc[nt] = __builtin_amdgcn_mfma_f32_16x16x32_bf16(ah, bh, acc[nt], 0, 0, 0);
        acc[nt] = __builtin_amdgcn_mfma_f32_16x16x32_bf16(ah, bl, acc[nt], 0, 0, 0);
        if (ASPLIT)
          acc[nt] = __builtin_amdgcn_mfma_f32_16x16x32_bf16(al, bh, acc[nt], 0, 0, 0);
      }
    }
    __syncthreads();
  }
#pragma unroll
  for (int nt = 0; nt < 8; nt++) {
    const int col = 128 * hh + 16 * nt + l15;
    const float bv = bias[col];
#pragma unroll
    for (int i = 0; i < 4; i++) {
      const int row = row0 + 16 * g + 4 * l4 + i;
      if (row < M) C[(size_t)row * 256 + col] = f2bf(silu_f(acc[nt][i] + bv));
    }
  }
}

// ---------------- final GEMM: C = A @ Wout + b, K=128, N=128, f32 in/out ----------------
__global__ __launch_bounds__(512)
void final_gemm(const float* __restrict__ A, const unsigned short* __restrict__ wh,
                const unsigned short* __restrict__ wl,
                const float* __restrict__ bias, float* __restrict__ C, int M)
{
  __shared__ unsigned short aTh[64 * 64], aTl[64 * 64];
  __shared__ unsigned short whb[128 * 64], wlb[128 * 64];
  const int tid = threadIdx.x;
  const int lane = tid & 63, wv = tid >> 6;
  const int g = wv & 3, hh = wv >> 2;
  const int l15 = lane & 15, l4 = lane >> 4;
  const int row0 = blockIdx.x * 64;
  const int r = tid >> 3, kseg = (tid & 7) * 8;
  const f32x4 zero4 = {0.f, 0.f, 0.f, 0.f};

  f32x4 acc[4];
#pragma unroll
  for (int nt = 0; nt < 4; nt++) acc[nt] = zero4;

  for (int kp = 0; kp < 2; kp++) {
    {
      const int grow = row0 + r;
      float x[8];
      if (grow < M) {
        const float* ap = A + (size_t)grow * 128 + kp * 64 + kseg;
        float4 v0 = *(const float4*)ap;
        float4 v1 = *(const float4*)(ap + 4);
        x[0] = v0.x; x[1] = v0.y; x[2] = v0.z; x[3] = v0.w;
        x[4] = v1.x; x[5] = v1.y; x[6] = v1.z; x[7] = v1.w;
      } else {
#pragma unroll
        for (int j = 0; j < 8; j++) x[j] = 0.f;
      }
      union { short8 s; unsigned short us[8]; } H, L;
#pragma unroll
      for (int j = 0; j < 8; j++) {
        H.us[j] = f2bf(x[j]);
        L.us[j] = f2bf(x[j] - bf2f(H.us[j]));
      }
      const int dst = r * 64 + ((((kseg >> 3) ^ (r & 7)) << 3));
      *(short8*)(aTh + dst) = H.s;
      *(short8*)(aTl + dst) = L.s;
    }
    {
      const short8* srcH = (const short8*)(wh + (size_t)kp * 8192);
      const short8* srcL = (const short8*)(wl + (size_t)kp * 8192);
#pragma unroll
      for (int i = 0; i < 2; i++) {
        ((short8*)whb)[tid + 512 * i] = srcH[tid + 512 * i];
        ((short8*)wlb)[tid + 512 * i] = srcL[tid + 512 * i];
      }
    }
    __syncthreads();
#pragma unroll
    for (int ks = 0; ks < 2; ks++) {
      const int arow = 16 * g + l15;
      const int aof = arow * 64 + (((4 * ks + l4) ^ (arow & 7)) << 3);
      short8 ah = *(const short8*)(aTh + aof);
      short8 al = *(const short8*)(aTl + aof);
#pragma unroll
      for (int nt = 0; nt < 4; nt++) {
        const int col = 64 * hh + 16 * nt + l15;
        const int bof = col * 64 + (((4 * ks + l4) ^ (col & 7)) << 3);
        short8 bh = *(const short8*)(whb + bof);
        short8 bl = *(const short8*)(wlb + bof);
        acc[nt] = __builtin_amdgcn_mfma_f32_16x16x32_bf16(ah, bh, acc[nt], 0, 0, 0);
        acc[nt] = __builtin_amdgcn_mfma_f32_16x16x32_bf16(ah, bl, acc[nt], 0, 0, 0);
        acc[nt] = __builtin_amdgcn_mfma_f32_16x16x32_bf16(al, bh, acc[nt], 0, 0, 0);
      }
    }
    __syncthreads();
  }
#pragma unroll
  for (int nt = 0; nt < 4; nt++) {
    const int col = 64 * hh + 16 * nt + l15;
    const float bv = bias[col];
#pragma unroll
    for (int i = 0; i < 4; i++) {
      const int row = row0 + 16 * g + 4 * l4 + i;
      if (row < M) C[(size_t)row * 128 + col] = acc[nt][i] + bv;
    }
  }
}

// ---------------- counting sort of idx_ji (proven 3-kernel scan) ----------------
__global__ void hist_k(const int* __restrict__ ji, int* __restrict__ cnt, int T) {
  int t = blockIdx.x * 256 + threadIdx.x;
  const int stride = gridDim.x * 256;
  for (; t < T; t += stride) atomicAdd(&cnt[ji[t]], 1);
}

__global__ void scan1_k(const int* __restrict__ cnt, int* __restrict__ csum, int E) {
  __shared__ int red[256];
  const int c0 = blockIdx.x * 2048;
  int s = 0;
  for (int i = threadIdx.x; i < 2048; i += 256) {
    int e = c0 + i;
    if (e < E) s += cnt[e];
  }
  red[threadIdx.x] = s;
  __syncthreads();
  for (int o = 128; o > 0; o >>= 1) {
    if (threadIdx.x < o) red[threadIdx.x] += red[threadIdx.x + o];
    __syncthreads();
  }
  if (threadIdx.x == 0) csum[blockIdx.x] = red[0];
}

__global__ void scan2_k(int* __restrict__ csum, int n) {
  if (threadIdx.x == 0 && blockIdx.x == 0) {
    int acc = 0;
    for (int i = 0; i < n; i++) { int v = csum[i]; csum[i] = acc; acc += v; }
  }
}

__global__ void scan3_k(const int* __restrict__ cnt, const int* __restrict__ csum,
                        int* __restrict__ off, int E) {
  __shared__ int ts[256];
  const int c0 = blockIdx.x * 2048;
  const int tid = threadIdx.x;
  int loc[8];
  int s = 0;
#pragma unroll
  for (int k = 0; k < 8; k++) {
    int e = c0 + tid * 8 + k;
    loc[k] = (e < E) ? cnt[e] : 0;
    s += loc[k];
  }
  ts[tid] = s;
  __syncthreads();
  for (int o = 1; o < 256; o <<= 1) {
    int v = (tid >= o) ? ts[tid - o] : 0;
    __syncthreads();
    ts[tid] += v;
    __syncthreads();
  }
  int base = csum[blockIdx.x] + ((tid > 0) ? ts[tid - 1] : 0);
#pragma unroll
  for (int k = 0; k < 8; k++) {
    int e = c0 + tid * 8 + k;
    if (e < E) { off[e] = base; base += loc[k]; }
  }
}

__global__ void scatter_k(const int* __restrict__ ji, int* __restrict__ cursor,
                          int* __restrict__ perm, int T) {
  int t = blockIdx.x * 256 + threadIdx.x;
  const int stride = gridDim.x * 256;
  for (; t < T; t += stride) {
    int e = ji[t];
    int p = atomicAdd(&cursor[e], 1);
    perm[p] = t;
  }
}

// ---------------- fused triplet kernel: wave-independent 16-row subwindows ----------------
__device__ __forceinline__ short8 pack8p(const short8 a, const short8 b,
                                         const float4 m0, const float4 m1)
{
  float p0 = bf2f((unsigned short)a[0]) * m0.x * bf2f((unsigned short)b[0]);
  float p1 = bf2f((unsigned short)a[1]) * m0.y * bf2f((unsigned short)b[1]);
  float p2 = bf2f((unsigned short)a[2]) * m0.z * bf2f((unsigned short)b[2]);
  float p3 = bf2f((unsigned short)a[3]) * m0.w * bf2f((unsigned short)b[3]);
  float p4 = bf2f((unsigned short)a[4]) * m1.x * bf2f((unsigned short)b[4]);
  float p5 = bf2f((unsigned short)a[5]) * m1.y * bf2f((unsigned short)b[5]);
  float p6 = bf2f((unsigned short)a[6]) * m1.z * bf2f((unsigned short)b[6]);
  float p7 = bf2f((unsigned short)a[7]) * m1.w * bf2f((unsigned short)b[7]);
  union { short8 s; unsigned u[4]; } t;
  t.u[0] = cvtpk_bf16(p0, p1);
  t.u[1] = cvtpk_bf16(p2, p3);
  t.u[2] = cvtpk_bf16(p4, p5);
  t.u[3] = cvtpk_bf16(p6, p7);
  return t.s;
}

// Requires T % 16 == 0 (T = 1e6 -> 62500 subwindows of 16 sorted rows).
__global__ __launch_bounds__(512, 2)
void triplet_fused(const unsigned short* __restrict__ h,
                   const float* __restrict__ M01, const float* __restrict__ M02,
                   const float* __restrict__ Ws01, const float* __restrict__ bs01,
                   const float* __restrict__ Ws02, const float* __restrict__ bs02,
                   const float* __restrict__ Ws,   const float* __restrict__ bs,
                   const int* __restrict__ idx_ji, const int* __restrict__ idx_ki,
                   const int* __restrict__ perm,
                   float* __restrict__ out_acc, int T)
{
  // weights in MFMA-fragment order: elem((ct*4+ks)*64 + lane)*8 + j -> conflict-free B reads
  __shared__ unsigned short wF01[16384];   // 32 KB
  __shared__ unsigned short wF02[16384];   // 32 KB
  __shared__ unsigned short wFA[16384];    // 32 KB (Ws rows 0..127)
  __shared__ unsigned short wFB[16384];    // 32 KB (Ws rows 128..255)
  __shared__ unsigned short sbuf[8][2048]; // 4 KB per wave (16 rows x 128 cols bf16)

  const int tid = threadIdx.x;
  for (int e = tid; e < 16384; e += 512) {
    const int j = e & 7, ln = (e >> 3) & 63, ks = (e >> 9) & 3, ct = e >> 11;
    const int col = 16 * ct + (ln & 15);
    const int k = 32 * ks + 8 * (ln >> 4) + j;
    const int src = k * 128 + col;
    wF01[e] = f2bf(Ws01[src]);
    wF02[e] = f2bf(Ws02[src]);
    wFA[e]  = f2bf(Ws[src]);
    wFB[e]  = f2bf(Ws[16384 + src]);
  }
  __syncthreads();  // only barrier in the kernel

  const int lane = tid & 63, wv = tid >> 6;
  const int l15 = lane & 15, l4 = lane >> 4;
  unsigned short* const sb = sbuf[wv];

  float bs01v[8], bs02v[8], bsv[8];
#pragma unroll
  for (int ct = 0; ct < 8; ct++) {
    bs01v[ct] = bs01[16 * ct + l15];
    bs02v[ct] = bs02[16 * ct + l15];
    bsv[ct]   = bs[16 * ct + l15];
  }

  const int nsub = T >> 4;
  const int stride = gridDim.x * 8;
  int sub = blockIdx.x * 8 + wv;

  // prologue: first subwindow's indices
  int pidx = perm[(sub << 4) + l15];
  int ek = idx_ki[pidx], ej = idx_ji[pidx];

  for (; sub < nsub; sub += stride) {
    // ---- issue ALL gathers for this subwindow (per-lane row l15, k-slices 8*l4) ----
    const unsigned short* fa = h + (size_t)ek * 256 + 8 * l4;
    const unsigned short* fb = h + (size_t)ej * 256 + 8 * l4;
    const float* mm1 = M01 + (size_t)pidx * 128 + 8 * l4;
    const float* mm2 = M02 + (size_t)pidx * 128 + 8 * l4;
    short8 ra1[4], rb1[4], ra2[4], rb2[4];
    float4 rm1[8], rm2[8];
#pragma unroll
    for (int ks = 0; ks < 4; ks++) {
      ra1[ks] = *(const short8*)(fa + 32 * ks);
      rb1[ks] = *(const short8*)(fb + 32 * ks);
      rm1[2 * ks]     = *(const float4*)(mm1 + 32 * ks);
      rm1[2 * ks + 1] = *(const float4*)(mm1 + 32 * ks + 4);
      ra2[ks] = *(const short8*)(fa + 128 + 32 * ks);
      rb2[ks] = *(const short8*)(fb + 128 + 32 * ks);
      rm2[2 * ks]     = *(const float4*)(mm2 + 32 * ks);
      rm2[2 * ks + 1] = *(const float4*)(mm2 + 32 * ks + 4);
    }

    // prefetch next subwindow's perm entry (dependent idx loads issued mid-body)
    const int subn = sub + stride;
    int sidx = (subn << 4) + l15;
    if (sidx >= T) sidx = T - 1;             // clamp; values unused past end
    const int pidx_n = perm[sidx];

    // ---- MFMA1: p01 @ Ws01 -> acc1[8]; bias folded into C-init ----
    f32x4 acc1[8];
#pragma unroll
    for (int ct = 0; ct < 8; ct++) {
      const float b = bs01v[ct];
      acc1[ct] = (f32x4){b, b, b, b};
    }
    __builtin_amdgcn_s_setprio(1);
#pragma unroll
    for (int ks = 0; ks < 4; ks++) {
      const short8 a = pack8p(ra1[ks], rb1[ks], rm1[2 * ks], rm1[2 * ks + 1]);
#pragma unroll
      for (int ct = 0; ct < 8; ct++) {
        const short8 b = *(const short8*)(wF01 + ((ct * 4 + ks) * 64 + lane) * 8);
        acc1[ct] = __builtin_amdgcn_mfma_f32_16x16x32_bf16(a, b, acc1[ct], 0, 0, 0);
      }
    }
    __builtin_amdgcn_s_setprio(0);

    // ---- s01 = silu(acc1) -> wave-private sbuf (chunk-XOR swizzle, cvt_pk pairs) ----
#pragma unroll
    for (int ct = 0; ct < 8; ct++) {
      const int chi = 2 * ct + (l15 >> 3);
      const float s0 = silu_f(acc1[ct][0]);
      const float s1 = silu_f(acc1[ct][1]);
      const float s2 = silu_f(acc1[ct][2]);
      const float s3 = silu_f(acc1[ct][3]);
      const unsigned u01 = cvtpk_bf16(s0, s1);
      const unsigned u23 = cvtpk_bf16(s2, s3);
      const int r0 = 4 * l4;
      sb[(r0 + 0) * 128 + (((chi ^ ((r0 + 0) & 7)) << 3)) + (l15 & 7)] = (unsigned short)u01;
      sb[(r0 + 1) * 128 + (((chi ^ ((r0 + 1) & 7)) << 3)) + (l15 & 7)] = (unsigned short)(u01 >> 16);
      sb[(r0 + 2) * 128 + (((chi ^ ((r0 + 2) & 7)) << 3)) + (l15 & 7)] = (unsigned short)u23;
      sb[(r0 + 3) * 128 + (((chi ^ ((r0 + 3) & 7)) << 3)) + (l15 & 7)] = (unsigned short)(u23 >> 16);
    }
    LGKM_SB();
    short8 as1[4];
#pragma unroll
    for (int ks = 0; ks < 4; ks++)
      as1[ks] = *(const short8*)(sb + l15 * 128 + (((4 * ks + l4) ^ (l15 & 7)) << 3));

    // ---- MFMA2: s01 @ WsA -> acc3[8]; final bias folded into C-init ----
    f32x4 acc3[8];
#pragma unroll
    for (int ct = 0; ct < 8; ct++) {
      const float b = bsv[ct];
      acc3[ct] = (f32x4){b, b, b, b};
    }
    __builtin_amdgcn_s_setprio(1);
#pragma unroll
    for (int ks = 0; ks < 4; ks++)
#pragma unroll
      for (int ct = 0; ct < 8; ct++) {
        const short8 b = *(const short8*)(wFA + ((ct * 4 + ks) * 64 + lane) * 8);
        acc3[ct] = __builtin_amdgcn_mfma_f32_16x16x32_bf16(as1[ks], b, acc3[ct], 0, 0, 0);
      }
    __builtin_amdgcn_s_setprio(0);

    // next-subwindow dependent idx loads (covered by MFMA3..4)
    const int ekn = idx_ki[pidx_n], ejn = idx_ji[pidx_n];

    // ---- MFMA3: p02 @ Ws02 -> acc1 (reuse); bias folded ----
#pragma unroll
    for (int ct = 0; ct < 8; ct++) {
      const float b = bs02v[ct];
      acc1[ct] = (f32x4){b, b, b, b};
    }
    __builtin_amdgcn_s_setprio(1);
#pragma unroll
    for (int ks = 0; ks < 4; ks++) {
      const short8 a = pack8p(ra2[ks], rb2[ks], rm2[2 * ks], rm2[2 * ks + 1]);
#pragma unroll
      for (int ct = 0; ct < 8; ct++) {
        const short8 b = *(const short8*)(wF02 + ((ct * 4 + ks) * 64 + lane) * 8);
        acc1[ct] = __builtin_amdgcn_mfma_f32_16x16x32_bf16(a, b, acc1[ct], 0, 0, 0);
      }
    }
    __builtin_amdgcn_s_setprio(0);

    // ---- s02 -> sbuf (as1 already consumed; wave-private, no WAR hazard) ----
#pragma unroll
    for (int ct = 0; ct < 8; ct++) {
      const int chi = 2 * ct + (l15 >> 3);
      const float s0 = silu_f(acc1[ct][0]);
      const float s1 = silu_f(acc1[ct][1]);
      const float s2 = silu_f(acc1[ct][2]);
      const float s3 = silu_f(acc1[ct][3]);
      const unsigned u01 = cvtpk_bf16(s0, s1);
      const unsigned u23 = cvtpk_bf16(s2, s3);
      const int r0 = 4 * l4;
      sb[(r0 + 0) * 128 + (((chi ^ ((r0 + 0) & 7)) << 3)) + (l15 & 7)] = (unsigned short)u01;
      sb[(r0 + 1) * 128 + (((chi ^ ((r0 + 1) & 7)) << 3)) + (l15 & 7)] = (unsigned short)(u01 >> 16);
      sb[(r0 + 2) * 128 + (((chi ^ ((r0 + 2) & 7)) << 3)) + (l15 & 7)] = (unsigned short)u23;
      sb[(r0 + 3) * 128 + (((chi ^ ((r0 + 3) & 7)) << 3)) + (l15 & 7)] = (unsigned short)(u23 >> 16);
    }
    LGKM_SB();
    short8 as2[4];
#pragma unroll
    for (int ks = 0; ks < 4; ks++)
      as2[ks] = *(const short8*)(sb + l15 * 128 + (((4 * ks + l4) ^ (l15 & 7)) << 3));

    // ---- MFMA4: s02 @ WsB -> acc3 += ----
    __builtin_amdgcn_s_setprio(1);
#pragma unroll
    for (int ks = 0; ks < 4; ks++)
#pragma unroll
      for (int ct = 0; ct < 8; ct++) {
        const short8 b = *(const short8*)(wFB + ((ct * 4 + ks) * 64 + lane) * 8);
        acc3[ct] = __builtin_amdgcn_mfma_f32_16x16x32_bf16(as2[ks], b, acc3[ct], 0, 0, 0);
      }
    __builtin_amdgcn_s_setprio(0);

    // ---- sfin = silu(acc3) in place (bias already folded) ----
#pragma unroll
    for (int ct = 0; ct < 8; ct++)
#pragma unroll
      for (int i = 0; i < 4; i++)
        acc3[ct][i] = silu_f(acc3[ct][i]);

    // ---- register segment-sum over 16 sorted rows ----
    {
      const int ejp = __shfl_up(ej, 1, 16);
      unsigned bm = (unsigned)(__ballot((l15 > 0) && (ej != ejp)) & 0xFFFFull);
      int fr = 0;
      unsigned rem = bm;
      while (fr < 16) {
        const int nxt = rem ? (__ffs(rem) - 1) : 16;
        rem &= rem - 1;
        const int lr = nxt - 1;
        const int e = __shfl(ej, fr, 16);
        float sv[8];
#pragma unroll
        for (int ct = 0; ct < 8; ct++) {
          float s = 0.f;
#pragma unroll
          for (int i = 0; i < 4; i++) {
            const int rr = 4 * l4 + i;
            s += (rr >= fr && rr <= lr) ? acc3[ct][i] : 0.f;
          }
          s += __shfl_xor(s, 16);
          s += __shfl_xor(s, 32);
          sv[ct] = s;
        }
        float w0, w1;
        if (l4 == 0)      { w0 = sv[0]; w1 = sv[1]; }
        else if (l4 == 1) { w0 = sv[2]; w1 = sv[3]; }
        else if (l4 == 2) { w0 = sv[4]; w1 = sv[5]; }
        else              { w0 = sv[6]; w1 = sv[7]; }
        float* dst = out_acc + (size_t)e * 128 + 32 * l4 + l15;
        if (fr == 0 || lr == 15) {   // run may continue into adjacent subwindow
          atomicAdd(dst, w0);
          atomicAdd(dst + 16, w1);
        } else {                     // strictly interior -> exclusive
          dst[0] = w0;
          dst[16] = w1;
        }
        fr = nxt;
      }
    }

    pidx = pidx_n; ek = ekn; ej = ejn;
  }
}

extern "C" void kernel_launch(void* const* d_in, const int* in_sizes, int n_in,
                              void* d_out, int out_size, void* d_ws, size_t ws_size,
                              hipStream_t stream)
{
  const float* f    = (const float*)d_in[0];
  const float* M01  = (const float*)d_in[1];
  const float* M02  = (const float*)d_in[2];
  const float* W1   = (const float*)d_in[3];
  const float* b1   = (const float*)d_in[4];
  const float* W2   = (const float*)d_in[5];
  const float* b2   = (const float*)d_in[6];
  const float* Ws01 = (const float*)d_in[7];
  const float* bs01 = (const float*)d_in[8];
  const float* Ws02 = (const float*)d_in[9];
  const float* bs02 = (const float*)d_in[10];
  const float* Ws   = (const float*)d_in[11];
  const float* bs   = (const float*)d_in[12];
  const float* Wout = (const float*)d_in[13];
  const float* bout = (const float*)d_in[14];
  const int* idx_ji = (const int*)d_in[16];
  const int* idx_ki = (const int*)d_in[17];

  const int E = in_sizes[0] / 256;
  const int T = in_sizes[1] / 128;

  char* w = (char*)d_ws;
  unsigned short* hbuf = (unsigned short*)w;                       // [E][256] bf16
  size_t o = ((size_t)E * 256 * 2 + 255) & ~(size_t)255;
  unsigned short* wt1h = (unsigned short*)(w + o); o += 256 * 256 * 2;
  unsigned short* wt1l = (unsigned short*)(w + o); o += 256 * 256 * 2;
  unsigned short* wt2h = (unsigned short*)(w + o); o += 256 * 256 * 2;
  unsigned short* wt2l = (unsigned short*)(w + o); o += 256 * 256 * 2;
  unsigned short* wtoh = (unsigned short*)(w + o); o += 128 * 128 * 2;
  unsigned short* wtol = (unsigned short*)(w + o); o += 128 * 128 * 2;
  o = (o + 255) & ~(size_t)255;
  int* cnt = (int*)(w + o);  o += ((size_t)E * 4 + 255) & ~(size_t)255;
  int* off = (int*)(w + o);  o += ((size_t)E * 4 + 255) & ~(size_t)255;
  int* csum = (int*)(w + o); o += 4096;
  int* perm = (int*)(w + o);                                       // [T]

  float* out_acc = (float*)d_out;
  const int mb = (E + 63) / 64;

  prep_all<<<(256 * 256 + 255) / 256, 256, 0, stream>>>(W1, wt1h, wt1l,
                                                        W2, wt2h, wt2l,
                                                        Wout, wtoh, wtol);

  mlp_gemm<0, 1><<<mb, 512, 0, stream>>>(f, wt1h, wt1l, b1, hbuf, E);
  mlp_gemm<1, 0><<<mb, 512, 0, stream>>>(hbuf, wt2h, wt2l, b2, hbuf, E);

  hipMemsetAsync(cnt, 0, (size_t)E * 4, stream);
  hist_k<<<1024, 256, 0, stream>>>(idx_ji, cnt, T);
  const int nchunks = (E + 2047) / 2048;
  scan1_k<<<nchunks, 256, 0, stream>>>(cnt, csum, E);
  scan2_k<<<1, 64, 0, stream>>>(csum, nchunks);
  scan3_k<<<nchunks, 256, 0, stream>>>(cnt, csum, off, E);
  scatter_k<<<1024, 256, 0, stream>>>(idx_ji, off, perm, T);

  hipMemsetAsync(d_out, 0, (size_t)E * 128 * sizeof(float), stream);

  triplet_fused<<<256, 512, 0, stream>>>(hbuf, M01, M02, Ws01, bs01, Ws02, bs02,
                                         Ws, bs, idx_ji, idx_ki, perm, out_acc, T);

  final_gemm<<<mb, 512, 0, stream>>>(out_acc, wtoh, wtol, bout, out_acc, E);
}

// Round 15
// 777.884 us; speedup vs baseline: 3.6278x; 1.1806x over previous
//
#include <hip/hip_runtime.h>

typedef __attribute__((ext_vector_type(8))) short short8;
typedef __attribute__((ext_vector_type(4))) float f32x4;

__device__ __forceinline__ float silu_f(float x) { return x / (1.0f + __expf(-x)); }

__device__ __forceinline__ unsigned short f2bf(float x) {
  unsigned u = __float_as_uint(x);
  u += 0x7FFFu + ((u >> 16) & 1u);
  return (unsigned short)(u >> 16);
}
__device__ __forceinline__ float bf2f(unsigned short v) {
  return __uint_as_float(((unsigned)v) << 16);
}
__device__ __forceinline__ unsigned cvtpk_bf16(float lo, float hi) {
  unsigned r;
  asm("v_cvt_pk_bf16_f32 %0, %1, %2" : "=v"(r) : "v"(lo), "v"(hi));
  return r;
}

// same-wave LDS write->read fence (no inter-wave barrier); sched_barrier per rule #18
#define LGKM_SB() do { asm volatile("s_waitcnt lgkmcnt(0)" ::: "memory"); \
                       __builtin_amdgcn_sched_barrier(0); } while (0)

// ---------------- weight prep + idx histogram (fused) ----------------
__device__ __forceinline__ void prep_one(const float* __restrict__ W,
                                         unsigned short* __restrict__ wh,
                                         unsigned short* __restrict__ wl,
                                         int N, int e)
{
  int k = e / N, n = e % N;
  float w = W[e];
  unsigned short hi = f2bf(w);
  unsigned short lo = f2bf(w - bf2f(hi));
  int kp = k >> 6, kk = k & 63;
  size_t dst = (size_t)kp * N * 64 + (size_t)n * 64 + ((((kk >> 3) ^ (n & 7)) << 3)) + (kk & 7);
  wh[dst] = hi;
  wl[dst] = lo;
}

__global__ void prep_all(const float* __restrict__ W1, unsigned short* w1h, unsigned short* w1l,
                         const float* __restrict__ W2, unsigned short* w2h, unsigned short* w2l,
                         const float* __restrict__ Wo, unsigned short* woh, unsigned short* wol,
                         const int* __restrict__ ji, int* __restrict__ cnt, int T)
{
  int e = blockIdx.x * 256 + threadIdx.x;
  if (e < 256 * 256) {
    prep_one(W1, w1h, w1l, 256, e);
    prep_one(W2, w2h, w2l, 256, e);
  }
  if (e < 128 * 128) prep_one(Wo, woh, wol, 128, e);
  // fused histogram of idx_ji (cnt pre-zeroed by memset before this kernel)
  const int stride = gridDim.x * 256;
  for (int t = e; t < T; t += stride) atomicAdd(&cnt[ji[t]], 1);
}

// ---------------- MLP GEMM: C = silu(A @ W + b), K=256, N=256, bf16 out ----------------
template<int INBF, int ASPLIT>
__global__ __launch_bounds__(512)
void mlp_gemm(const void* A_, const unsigned short* __restrict__ wh,
              const unsigned short* __restrict__ wl,
              const float* __restrict__ bias, unsigned short* __restrict__ C, int M)
{
  __shared__ unsigned short aTh[64 * 64], aTl[64 * 64];
  __shared__ unsigned short whb[256 * 64], wlb[256 * 64];
  const int tid = threadIdx.x;
  const int lane = tid & 63, wv = tid >> 6;
  const int g = wv & 3, hh = wv >> 2;
  const int l15 = lane & 15, l4 = lane >> 4;
  const int row0 = blockIdx.x * 64;
  const int r = tid >> 3, kseg = (tid & 7) * 8;
  const f32x4 zero4 = {0.f, 0.f, 0.f, 0.f};

  f32x4 acc[8];
#pragma unroll
  for (int nt = 0; nt < 8; nt++) acc[nt] = zero4;

  for (int kp = 0; kp < 4; kp++) {
    {
      const int grow = row0 + r;
      float x[8];
      if (grow < M) {
        if (INBF) {
          short8 v = *(const short8*)((const unsigned short*)A_ + (size_t)grow * 256 + kp * 64 + kseg);
#pragma unroll
          for (int j = 0; j < 8; j++) x[j] = bf2f((unsigned short)v[j]);
        } else {
          const float* ap = (const float*)A_ + (size_t)grow * 256 + kp * 64 + kseg;
          float4 v0 = *(const float4*)ap;
          float4 v1 = *(const float4*)(ap + 4);
          x[0] = v0.x; x[1] = v0.y; x[2] = v0.z; x[3] = v0.w;
          x[4] = v1.x; x[5] = v1.y; x[6] = v1.z; x[7] = v1.w;
        }
      } else {
#pragma unroll
        for (int j = 0; j < 8; j++) x[j] = 0.f;
      }
      union { short8 s; unsigned short us[8]; } H, L;
#pragma unroll
      for (int j = 0; j < 8; j++) {
        H.us[j] = f2bf(x[j]);
        L.us[j] = ASPLIT ? f2bf(x[j] - bf2f(H.us[j])) : (unsigned short)0;
      }
      const int dst = r * 64 + ((((kseg >> 3) ^ (r & 7)) << 3));
      *(short8*)(aTh + dst) = H.s;
      if (ASPLIT) *(short8*)(aTl + dst) = L.s;
    }
    {
      const short8* srcH = (const short8*)(wh + (size_t)kp * 16384);
      const short8* srcL = (const short8*)(wl + (size_t)kp * 16384);
#pragma unroll
      for (int i = 0; i < 4; i++) {
        ((short8*)whb)[tid + 512 * i] = srcH[tid + 512 * i];
        ((short8*)wlb)[tid + 512 * i] = srcL[tid + 512 * i];
      }
    }
    __syncthreads();
#pragma unroll
    for (int ks = 0; ks < 2; ks++) {
      const int arow = 16 * g + l15;
      const int aof = arow * 64 + (((4 * ks + l4) ^ (arow & 7)) << 3);
      short8 ah = *(const short8*)(aTh + aof);
      short8 al = *(const short8*)(aTl + aof);
#pragma unroll
      for (int nt = 0; nt < 8; nt++) {
        const int col = 128 * hh + 16 * nt + l15;
        const int bof = col * 64 + (((4 * ks + l4) ^ (col & 7)) << 3);
        short8 bh = *(const short8*)(whb + bof);
        short8 bl = *(const short8*)(wlb + bof);
        acc[nt] = __builtin_amdgcn_mfma_f32_16x16x32_bf16(ah, bh, acc[nt], 0, 0, 0);
        acc[nt] = __builtin_amdgcn_mfma_f32_16x16x32_bf16(ah, bl, acc[nt], 0, 0, 0);
        if (ASPLIT)
          acc[nt] = __builtin_amdgcn_mfma_f32_16x16x32_bf16(al, bh, acc[nt], 0, 0, 0);
      }
    }
    __syncthreads();
  }
#pragma unroll
  for (int nt = 0; nt < 8; nt++) {
    const int col = 128 * hh + 16 * nt + l15;
    const float bv = bias[col];
#pragma unroll
    for (int i = 0; i < 4; i++) {
      const int row = row0 + 16 * g + 4 * l4 + i;
      if (row < M) C[(size_t)row * 256 + col] = f2bf(silu_f(acc[nt][i] + bv));
    }
  }
}

// ---------------- final GEMM: C = A @ Wout + b, K=128, N=128, f32 in/out ----------------
__global__ __launch_bounds__(512)
void final_gemm(const float* __restrict__ A, const unsigned short* __restrict__ wh,
                const unsigned short* __restrict__ wl,
                const float* __restrict__ bias, float* __restrict__ C, int M)
{
  __shared__ unsigned short aTh[64 * 64], aTl[64 * 64];
  __shared__ unsigned short whb[128 * 64], wlb[128 * 64];
  const int tid = threadIdx.x;
  const int lane = tid & 63, wv = tid >> 6;
  const int g = wv & 3, hh = wv >> 2;
  const int l15 = lane & 15, l4 = lane >> 4;
  const int row0 = blockIdx.x * 64;
  const int r = tid >> 3, kseg = (tid & 7) * 8;
  const f32x4 zero4 = {0.f, 0.f, 0.f, 0.f};

  f32x4 acc[4];
#pragma unroll
  for (int nt = 0; nt < 4; nt++) acc[nt] = zero4;

  for (int kp = 0; kp < 2; kp++) {
    {
      const int grow = row0 + r;
      float x[8];
      if (grow < M) {
        const float* ap = A + (size_t)grow * 128 + kp * 64 + kseg;
        float4 v0 = *(const float4*)ap;
        float4 v1 = *(const float4*)(ap + 4);
        x[0] = v0.x; x[1] = v0.y; x[2] = v0.z; x[3] = v0.w;
        x[4] = v1.x; x[5] = v1.y; x[6] = v1.z; x[7] = v1.w;
      } else {
#pragma unroll
        for (int j = 0; j < 8; j++) x[j] = 0.f;
      }
      union { short8 s; unsigned short us[8]; } H, L;
#pragma unroll
      for (int j = 0; j < 8; j++) {
        H.us[j] = f2bf(x[j]);
        L.us[j] = f2bf(x[j] - bf2f(H.us[j]));
      }
      const int dst = r * 64 + ((((kseg >> 3) ^ (r & 7)) << 3));
      *(short8*)(aTh + dst) = H.s;
      *(short8*)(aTl + dst) = L.s;
    }
    {
      const short8* srcH = (const short8*)(wh + (size_t)kp * 8192);
      const short8* srcL = (const short8*)(wl + (size_t)kp * 8192);
#pragma unroll
      for (int i = 0; i < 2; i++) {
        ((short8*)whb)[tid + 512 * i] = srcH[tid + 512 * i];
        ((short8*)wlb)[tid + 512 * i] = srcL[tid + 512 * i];
      }
    }
    __syncthreads();
#pragma unroll
    for (int ks = 0; ks < 2; ks++) {
      const int arow = 16 * g + l15;
      const int aof = arow * 64 + (((4 * ks + l4) ^ (arow & 7)) << 3);
      short8 ah = *(const short8*)(aTh + aof);
      short8 al = *(const short8*)(aTl + aof);
#pragma unroll
      for (int nt = 0; nt < 4; nt++) {
        const int col = 64 * hh + 16 * nt + l15;
        const int bof = col * 64 + (((4 * ks + l4) ^ (col & 7)) << 3);
        short8 bh = *(const short8*)(whb + bof);
        short8 bl = *(const short8*)(wlb + bof);
        acc[nt] = __builtin_amdgcn_mfma_f32_16x16x32_bf16(ah, bh, acc[nt], 0, 0, 0);
        acc[nt] = __builtin_amdgcn_mfma_f32_16x16x32_bf16(ah, bl, acc[nt], 0, 0, 0);
        acc[nt] = __builtin_amdgcn_mfma_f32_16x16x32_bf16(al, bh, acc[nt], 0, 0, 0);
      }
    }
    __syncthreads();
  }
#pragma unroll
  for (int nt = 0; nt < 4; nt++) {
    const int col = 64 * hh + 16 * nt + l15;
    const float bv = bias[col];
#pragma unroll
    for (int i = 0; i < 4; i++) {
      const int row = row0 + 16 * g + 4 * l4 + i;
      if (row < M) C[(size_t)row * 128 + col] = acc[nt][i] + bv;
    }
  }
}

// ---------------- counting sort of idx_ji (3-kernel scan; scan2 wave-parallel) ----------------
__global__ void scan1_k(const int* __restrict__ cnt, int* __restrict__ csum, int E) {
  __shared__ int red[256];
  const int c0 = blockIdx.x * 2048;
  int s = 0;
  for (int i = threadIdx.x; i < 2048; i += 256) {
    int e = c0 + i;
    if (e < E) s += cnt[e];
  }
  red[threadIdx.x] = s;
  __syncthreads();
  for (int o = 128; o > 0; o >>= 1) {
    if (threadIdx.x < o) red[threadIdx.x] += red[threadIdx.x + o];
    __syncthreads();
  }
  if (threadIdx.x == 0) csum[blockIdx.x] = red[0];
}

// exclusive scan of csum[0..n), n <= 64, one wave
__global__ void scan2_k(int* __restrict__ csum, int n) {
  const int lane = threadIdx.x;
  int v = (lane < n) ? csum[lane] : 0;
  const int orig = v;
  for (int o = 1; o < 64; o <<= 1) {
    int t = __shfl_up(v, o, 64);
    if (lane >= o) v += t;
  }
  if (lane < n) csum[lane] = v - orig;   // exclusive
}

__global__ void scan3_k(const int* __restrict__ cnt, const int* __restrict__ csum,
                        int* __restrict__ off, int E) {
  __shared__ int ts[256];
  const int c0 = blockIdx.x * 2048;
  const int tid = threadIdx.x;
  int loc[8];
  int s = 0;
#pragma unroll
  for (int k = 0; k < 8; k++) {
    int e = c0 + tid * 8 + k;
    loc[k] = (e < E) ? cnt[e] : 0;
    s += loc[k];
  }
  ts[tid] = s;
  __syncthreads();
  for (int o = 1; o < 256; o <<= 1) {
    int v = (tid >= o) ? ts[tid - o] : 0;
    __syncthreads();
    ts[tid] += v;
    __syncthreads();
  }
  int base = csum[blockIdx.x] + ((tid > 0) ? ts[tid - 1] : 0);
#pragma unroll
  for (int k = 0; k < 8; k++) {
    int e = c0 + tid * 8 + k;
    if (e < E) { off[e] = base; base += loc[k]; }
  }
}

__global__ void scatter_k(const int* __restrict__ ji, int* __restrict__ cursor,
                          int* __restrict__ perm, int T) {
  int t = blockIdx.x * 256 + threadIdx.x;
  const int stride = gridDim.x * 256;
  for (; t < T; t += stride) {
    int e = ji[t];
    int p = atomicAdd(&cursor[e], 1);
    perm[p] = t;
  }
}

// ---------------- fused triplet kernel: wave-independent 16-row subwindows ----------------
__device__ __forceinline__ short8 pack8p(const short8 a, const short8 b,
                                         const float4 m0, const float4 m1)
{
  float p0 = bf2f((unsigned short)a[0]) * m0.x * bf2f((unsigned short)b[0]);
  float p1 = bf2f((unsigned short)a[1]) * m0.y * bf2f((unsigned short)b[1]);
  float p2 = bf2f((unsigned short)a[2]) * m0.z * bf2f((unsigned short)b[2]);
  float p3 = bf2f((unsigned short)a[3]) * m0.w * bf2f((unsigned short)b[3]);
  float p4 = bf2f((unsigned short)a[4]) * m1.x * bf2f((unsigned short)b[4]);
  float p5 = bf2f((unsigned short)a[5]) * m1.y * bf2f((unsigned short)b[5]);
  float p6 = bf2f((unsigned short)a[6]) * m1.z * bf2f((unsigned short)b[6]);
  float p7 = bf2f((unsigned short)a[7]) * m1.w * bf2f((unsigned short)b[7]);
  union { short8 s; unsigned u[4]; } t;
  t.u[0] = cvtpk_bf16(p0, p1);
  t.u[1] = cvtpk_bf16(p2, p3);
  t.u[2] = cvtpk_bf16(p4, p5);
  t.u[3] = cvtpk_bf16(p6, p7);
  return t.s;
}

// Requires T % 16 == 0 (T = 1e6 -> 62500 subwindows of 16 sorted rows).
__global__ __launch_bounds__(512, 2)
void triplet_fused(const unsigned short* __restrict__ h,
                   const float* __restrict__ M01, const float* __restrict__ M02,
                   const float* __restrict__ Ws01, const float* __restrict__ bs01,
                   const float* __restrict__ Ws02, const float* __restrict__ bs02,
                   const float* __restrict__ Ws,   const float* __restrict__ bs,
                   const int* __restrict__ idx_ji, const int* __restrict__ idx_ki,
                   const int* __restrict__ perm,
                   float* __restrict__ out_acc, int T)
{
  // weights in MFMA-fragment order: elem((ct*4+ks)*64 + lane)*8 + j -> conflict-free B reads
  __shared__ unsigned short wF01[16384];   // 32 KB
  __shared__ unsigned short wF02[16384];   // 32 KB
  __shared__ unsigned short wFA[16384];    // 32 KB (Ws rows 0..127)
  __shared__ unsigned short wFB[16384];    // 32 KB (Ws rows 128..255)
  __shared__ unsigned short sbuf[8][2048]; // 4 KB per wave (16 rows x 128 cols bf16)

  const int tid = threadIdx.x;
  for (int e = tid; e < 16384; e += 512) {
    const int j = e & 7, ln = (e >> 3) & 63, ks = (e >> 9) & 3, ct = e >> 11;
    const int col = 16 * ct + (ln & 15);
    const int k = 32 * ks + 8 * (ln >> 4) + j;
    const int src = k * 128 + col;
    wF01[e] = f2bf(Ws01[src]);
    wF02[e] = f2bf(Ws02[src]);
    wFA[e]  = f2bf(Ws[src]);
    wFB[e]  = f2bf(Ws[16384 + src]);
  }
  __syncthreads();  // only barrier in the kernel

  const int lane = tid & 63, wv = tid >> 6;
  const int l15 = lane & 15, l4 = lane >> 4;
  unsigned short* const sb = sbuf[wv];
  const f32x4 zero4 = {0.f, 0.f, 0.f, 0.f};

  float bs01v[8], bs02v[8], bsv[8];
#pragma unroll
  for (int ct = 0; ct < 8; ct++) {
    bs01v[ct] = bs01[16 * ct + l15];
    bs02v[ct] = bs02[16 * ct + l15];
    bsv[ct]   = bs[16 * ct + l15];
  }

  const int nsub = T >> 4;
  const int stride = gridDim.x * 8;
  int sub = blockIdx.x * 8 + wv;

  // prologue: first subwindow's indices
  int pidx = perm[(sub << 4) + l15];
  int ek = idx_ki[pidx], ej = idx_ji[pidx];

  for (; sub < nsub; sub += stride) {
    // ---- issue ALL gathers for this subwindow (per-lane row l15, k-slices 8*l4) ----
    const unsigned short* fa = h + (size_t)ek * 256 + 8 * l4;
    const unsigned short* fb = h + (size_t)ej * 256 + 8 * l4;
    const float* mm1 = M01 + (size_t)pidx * 128 + 8 * l4;
    const float* mm2 = M02 + (size_t)pidx * 128 + 8 * l4;
    short8 ra1[4], rb1[4], ra2[4], rb2[4];
    float4 rm1[8], rm2[8];
#pragma unroll
    for (int ks = 0; ks < 4; ks++) {
      ra1[ks] = *(const short8*)(fa + 32 * ks);
      rb1[ks] = *(const short8*)(fb + 32 * ks);
      rm1[2 * ks]     = *(const float4*)(mm1 + 32 * ks);
      rm1[2 * ks + 1] = *(const float4*)(mm1 + 32 * ks + 4);
      ra2[ks] = *(const short8*)(fa + 128 + 32 * ks);
      rb2[ks] = *(const short8*)(fb + 128 + 32 * ks);
      rm2[2 * ks]     = *(const float4*)(mm2 + 32 * ks);
      rm2[2 * ks + 1] = *(const float4*)(mm2 + 32 * ks + 4);
    }

    // prefetch next subwindow's perm entry (dependent idx loads issued mid-body)
    const int subn = sub + stride;
    int sidx = (subn << 4) + l15;
    if (sidx >= T) sidx = T - 1;             // clamp; values unused past end
    const int pidx_n = perm[sidx];

    // ---- MFMA1: p01 @ Ws01 -> acc1[8] (16 rows x 128 cols) ----
    f32x4 acc1[8];
#pragma unroll
    for (int ct = 0; ct < 8; ct++) acc1[ct] = zero4;
    __builtin_amdgcn_s_setprio(1);
#pragma unroll
    for (int ks = 0; ks < 4; ks++) {
      const short8 a = pack8p(ra1[ks], rb1[ks], rm1[2 * ks], rm1[2 * ks + 1]);
#pragma unroll
      for (int ct = 0; ct < 8; ct++) {
        const short8 b = *(const short8*)(wF01 + ((ct * 4 + ks) * 64 + lane) * 8);
        acc1[ct] = __builtin_amdgcn_mfma_f32_16x16x32_bf16(a, b, acc1[ct], 0, 0, 0);
      }
    }
    __builtin_amdgcn_s_setprio(0);

    // ---- s01 = silu(acc1+bs01) -> wave-private sbuf (chunk-XOR swizzle) ----
#pragma unroll
    for (int ct = 0; ct < 8; ct++) {
      const int chi = 2 * ct + (l15 >> 3);
#pragma unroll
      for (int i = 0; i < 4; i++) {
        const int row = 4 * l4 + i;
        sb[row * 128 + (((chi ^ (row & 7)) << 3)) + (l15 & 7)] =
            f2bf(silu_f(acc1[ct][i] + bs01v[ct]));
      }
    }
    LGKM_SB();
    short8 as1[4];
#pragma unroll
    for (int ks = 0; ks < 4; ks++)
      as1[ks] = *(const short8*)(sb + l15 * 128 + (((4 * ks + l4) ^ (l15 & 7)) << 3));

    // ---- MFMA2: s01 @ WsA -> acc3[8] ----
    f32x4 acc3[8];
#pragma unroll
    for (int ct = 0; ct < 8; ct++) acc3[ct] = zero4;
    __builtin_amdgcn_s_setprio(1);
#pragma unroll
    for (int ks = 0; ks < 4; ks++)
#pragma unroll
      for (int ct = 0; ct < 8; ct++) {
        const short8 b = *(const short8*)(wFA + ((ct * 4 + ks) * 64 + lane) * 8);
        acc3[ct] = __builtin_amdgcn_mfma_f32_16x16x32_bf16(as1[ks], b, acc3[ct], 0, 0, 0);
      }
    __builtin_amdgcn_s_setprio(0);

    // next-subwindow dependent idx loads (covered by MFMA3..4)
    const int ekn = idx_ki[pidx_n], ejn = idx_ji[pidx_n];

    // ---- MFMA3: p02 @ Ws02 -> acc1 (reuse) ----
#pragma unroll
    for (int ct = 0; ct < 8; ct++) acc1[ct] = zero4;
    __builtin_amdgcn_s_setprio(1);
#pragma unroll
    for (int ks = 0; ks < 4; ks++) {
      const short8 a = pack8p(ra2[ks], rb2[ks], rm2[2 * ks], rm2[2 * ks + 1]);
#pragma unroll
      for (int ct = 0; ct < 8; ct++) {
        const short8 b = *(const short8*)(wF02 + ((ct * 4 + ks) * 64 + lane) * 8);
        acc1[ct] = __builtin_amdgcn_mfma_f32_16x16x32_bf16(a, b, acc1[ct], 0, 0, 0);
      }
    }
    __builtin_amdgcn_s_setprio(0);

    // ---- s02 -> sbuf (as1 already consumed; wave-private, no WAR hazard) ----
#pragma unroll
    for (int ct = 0; ct < 8; ct++) {
      const int chi = 2 * ct + (l15 >> 3);
#pragma unroll
      for (int i = 0; i < 4; i++) {
        const int row = 4 * l4 + i;
        sb[row * 128 + (((chi ^ (row & 7)) << 3)) + (l15 & 7)] =
            f2bf(silu_f(acc1[ct][i] + bs02v[ct]));
      }
    }
    LGKM_SB();
    short8 as2[4];
#pragma unroll
    for (int ks = 0; ks < 4; ks++)
      as2[ks] = *(const short8*)(sb + l15 * 128 + (((4 * ks + l4) ^ (l15 & 7)) << 3));

    // ---- MFMA4: s02 @ WsB -> acc3 += ----
    __builtin_amdgcn_s_setprio(1);
#pragma unroll
    for (int ks = 0; ks < 4; ks++)
#pragma unroll
      for (int ct = 0; ct < 8; ct++) {
        const short8 b = *(const short8*)(wFB + ((ct * 4 + ks) * 64 + lane) * 8);
        acc3[ct] = __builtin_amdgcn_mfma_f32_16x16x32_bf16(as2[ks], b, acc3[ct], 0, 0, 0);
      }
    __builtin_amdgcn_s_setprio(0);

    // ---- sfin = silu(acc3 + bs) in place ----
#pragma unroll
    for (int ct = 0; ct < 8; ct++)
#pragma unroll
      for (int i = 0; i < 4; i++)
        acc3[ct][i] = silu_f(acc3[ct][i] + bsv[ct]);

    // ---- register segment-sum over 16 sorted rows ----
    {
      const int ejp = __shfl_up(ej, 1, 16);
      unsigned bm = (unsigned)(__ballot((l15 > 0) && (ej != ejp)) & 0xFFFFull);
      int fr = 0;
      unsigned rem = bm;
      while (fr < 16) {
        const int nxt = rem ? (__ffs(rem) - 1) : 16;
        rem &= rem - 1;
        const int lr = nxt - 1;
        const int e = __shfl(ej, fr, 16);
        float sv[8];
#pragma unroll
        for (int ct = 0; ct < 8; ct++) {
          float s = 0.f;
#pragma unroll
          for (int i = 0; i < 4; i++) {
            const int rr = 4 * l4 + i;
            s += (rr >= fr && rr <= lr) ? acc3[ct][i] : 0.f;
          }
          s += __shfl_xor(s, 16);
          s += __shfl_xor(s, 32);
          sv[ct] = s;
        }
        float w0, w1;
        if (l4 == 0)      { w0 = sv[0]; w1 = sv[1]; }
        else if (l4 == 1) { w0 = sv[2]; w1 = sv[3]; }
        else if (l4 == 2) { w0 = sv[4]; w1 = sv[5]; }
        else              { w0 = sv[6]; w1 = sv[7]; }
        float* dst = out_acc + (size_t)e * 128 + 32 * l4 + l15;
        if (fr == 0 || lr == 15) {   // run may continue into adjacent subwindow
          atomicAdd(dst, w0);
          atomicAdd(dst + 16, w1);
        } else {                     // strictly interior -> exclusive
          dst[0] = w0;
          dst[16] = w1;
        }
        fr = nxt;
      }
    }

    pidx = pidx_n; ek = ekn; ej = ejn;
  }
}

extern "C" void kernel_launch(void* const* d_in, const int* in_sizes, int n_in,
                              void* d_out, int out_size, void* d_ws, size_t ws_size,
                              hipStream_t stream)
{
  const float* f    = (const float*)d_in[0];
  const float* M01  = (const float*)d_in[1];
  const float* M02  = (const float*)d_in[2];
  const float* W1   = (const float*)d_in[3];
  const float* b1   = (const float*)d_in[4];
  const float* W2   = (const float*)d_in[5];
  const float* b2   = (const float*)d_in[6];
  const float* Ws01 = (const float*)d_in[7];
  const float* bs01 = (const float*)d_in[8];
  const float* Ws02 = (const float*)d_in[9];
  const float* bs02 = (const float*)d_in[10];
  const float* Ws   = (const float*)d_in[11];
  const float* bs   = (const float*)d_in[12];
  const float* Wout = (const float*)d_in[13];
  const float* bout = (const float*)d_in[14];
  const int* idx_ji = (const int*)d_in[16];
  const int* idx_ki = (const int*)d_in[17];

  const int E = in_sizes[0] / 256;
  const int T = in_sizes[1] / 128;

  char* w = (char*)d_ws;
  unsigned short* hbuf = (unsigned short*)w;                       // [E][256] bf16
  size_t o = ((size_t)E * 256 * 2 + 255) & ~(size_t)255;
  unsigned short* wt1h = (unsigned short*)(w + o); o += 256 * 256 * 2;
  unsigned short* wt1l = (unsigned short*)(w + o); o += 256 * 256 * 2;
  unsigned short* wt2h = (unsigned short*)(w + o); o += 256 * 256 * 2;
  unsigned short* wt2l = (unsigned short*)(w + o); o += 256 * 256 * 2;
  unsigned short* wtoh = (unsigned short*)(w + o); o += 128 * 128 * 2;
  unsigned short* wtol = (unsigned short*)(w + o); o += 128 * 128 * 2;
  o = (o + 255) & ~(size_t)255;
  int* cnt = (int*)(w + o);  o += ((size_t)E * 4 + 255) & ~(size_t)255;
  int* off = (int*)(w + o);  o += ((size_t)E * 4 + 255) & ~(size_t)255;
  int* csum = (int*)(w + o); o += 4096;
  int* perm = (int*)(w + o);                                       // [T]

  float* out_acc = (float*)d_out;
  const int mb = (E + 63) / 64;

  // cnt must be zero before prep_all's fused histogram
  hipMemsetAsync(cnt, 0, (size_t)E * 4, stream);
  prep_all<<<(256 * 256 + 255) / 256, 256, 0, stream>>>(W1, wt1h, wt1l,
                                                        W2, wt2h, wt2l,
                                                        Wout, wtoh, wtol,
                                                        idx_ji, cnt, T);

  mlp_gemm<0, 1><<<mb, 512, 0, stream>>>(f, wt1h, wt1l, b1, hbuf, E);
  mlp_gemm<1, 0><<<mb, 512, 0, stream>>>(hbuf, wt2h, wt2l, b2, hbuf, E);

  const int nchunks = (E + 2047) / 2048;
  scan1_k<<<nchunks, 256, 0, stream>>>(cnt, csum, E);
  scan2_k<<<1, 64, 0, stream>>>(csum, nchunks);
  scan3_k<<<nchunks, 256, 0, stream>>>(cnt, csum, off, E);
  scatter_k<<<1024, 256, 0, stream>>>(idx_ji, off, perm, T);

  hipMemsetAsync(d_out, 0, (size_t)E * 128 * sizeof(float), stream);

  triplet_fused<<<256, 512, 0, stream>>>(hbuf, M01, M02, Ws01, bs01, Ws02, bs02,
                                         Ws, bs, idx_ji, idx_ki, perm, out_acc, T);

  final_gemm<<<mb, 512, 0, stream>>>(out_acc, wtoh, wtol, bout, out_acc, E);
}